// Round 9
// baseline (170.196 us; speedup 1.0000x reference)
//
#include <hip/hip_runtime.h>
#include <hip/hip_bf16.h>

#define HW_   2304
#define WDIM  48
#define CDIM  128
#define NTOK  18432
#define DHW   9216
#define BCDHW 1179648

typedef __attribute__((ext_vector_type(8))) short short8;
typedef __attribute__((ext_vector_type(4))) short sh4;
typedef __attribute__((ext_vector_type(4))) float f32x4;
typedef __attribute__((ext_vector_type(4))) unsigned short us4;
typedef unsigned short u16;

__device__ __forceinline__ u16 f2bf(float f) {
  union { float f; unsigned u; } v; v.f = f;
  unsigned r = v.u + 0x7FFFu + ((v.u >> 16) & 1u);
  return (u16)(r >> 16);
}
__device__ __forceinline__ float bf2f(u16 b) {
  union { unsigned u; float f; } v; v.u = ((unsigned)b) << 16; return v.f;
}

// ---------- NEW (single variable this round): fused transpose-in + LN1 ----------
// x(B,C,D,H,W) -> t0(tok,128) f32   AND   lnb(tok,128) bf16
__global__ __launch_bounds__(256) void k_fusein2(const float* __restrict__ x,
                                                 const float* __restrict__ w,
                                                 const float* __restrict__ b,
                                                 float* __restrict__ t0,
                                                 u16* __restrict__ lnb) {
  __shared__ float tile[64][129];
  int tid = threadIdx.x;
  int tok0 = blockIdx.x * 64;
  int bd = tok0 / HW_, s0 = tok0 % HW_;
  int bb = bd >> 2, dd = bd & 3;
  size_t xb = (size_t)bb * BCDHW + (size_t)dd * HW_ + s0;
#pragma unroll
  for (int rnd = 0; rnd < 8; ++rnd) {
    int c = (rnd & 1) * 64 + (tid >> 2);
    int s = (rnd >> 1) * 16 + (tid & 3) * 4;
    float4 v = *(const float4*)&x[xb + (size_t)c * DHW + s];
    tile[s][c] = v.x; tile[s + 1][c] = v.y; tile[s + 2][c] = v.z; tile[s + 3][c] = v.w;
  }
  __syncthreads();
  int wv = tid >> 6, ln = tid & 63;
  float w0 = w[ln], w1 = w[ln + 64], b0 = b[ln], b1 = b[ln + 64];
  for (int i = 0; i < 16; ++i) {
    int tk = wv * 16 + i;
    float a = tile[tk][ln], c2 = tile[tk][ln + 64];
    size_t ob = (size_t)(tok0 + tk) * 128;
    t0[ob + ln] = a;
    t0[ob + ln + 64] = c2;
    float s = a + c2;
#pragma unroll
    for (int m = 1; m < 64; m <<= 1) s += __shfl_xor(s, m);
    float mu = s * 0.0078125f;
    float da = a - mu, db = c2 - mu;
    float ss = da * da + db * db;
#pragma unroll
    for (int m = 1; m < 64; m <<= 1) ss += __shfl_xor(ss, m);
    float rstd = rsqrtf(ss * 0.0078125f + 1e-5f);
    lnb[ob + ln] = f2bf(da * rstd * w0 + b0);
    lnb[ob + ln + 64] = f2bf(db * rstd * w1 + b1);
  }
}

// ---------------- PROVEN (round 2): weights fp32 -> bf16 ----------------
__global__ __launch_bounds__(256) void k_w2bf(const float* __restrict__ w0,
                                              const float* __restrict__ w1,
                                              const float* __restrict__ w2,
                                              const float* __restrict__ w3,
                                              u16* __restrict__ out) {
  int i = blockIdx.x * 256 + threadIdx.x;  // 131072 total
  float v;
  if (i < 49152) v = w0[i];
  else if (i < 65536) v = w1[i - 49152];
  else if (i < 98304) v = w2[i - 65536];
  else v = w3[i - 98304];
  out[i] = f2bf(v);
}

// ---------------- PROVEN (round 2): LayerNorm f32 -> bf16 ----------------
__global__ __launch_bounds__(256) void k_ln(const float* __restrict__ in,
                                            const float* __restrict__ w,
                                            const float* __restrict__ b,
                                            u16* __restrict__ out) {
  int tok = blockIdx.x * 4 + (threadIdx.x >> 6);
  int lane = threadIdx.x & 63;
  float2 v = *(const float2*)&in[(size_t)tok * CDIM + lane * 2];
  float s = v.x + v.y;
#pragma unroll
  for (int m = 1; m < 64; m <<= 1) s += __shfl_xor(s, m);
  float mean = s * 0.0078125f;
  float dx = v.x - mean, dy = v.y - mean;
  float ss = dx * dx + dy * dy;
#pragma unroll
  for (int m = 1; m < 64; m <<= 1) ss += __shfl_xor(ss, m);
  float rs = rsqrtf(ss * 0.0078125f + 1e-5f);
  unsigned p0 = f2bf(dx * rs * w[lane * 2] + b[lane * 2]);
  unsigned p1 = f2bf(dy * rs * w[lane * 2 + 1] + b[lane * 2 + 1]);
  *(unsigned*)&out[(size_t)tok * CDIM + lane * 2] = p0 | (p1 << 16);
}

// ---------------- PROVEN (round 2): bf16 MFMA GEMM, LDS-staged, XOR-swizzled ----------------
template <int ACT, int RES, int OUTBF>
__global__ __launch_bounds__(256) void k_gemm(const u16* __restrict__ A,
                                              const u16* __restrict__ W,
                                              const float* __restrict__ bias,
                                              const float* __restrict__ res,
                                              float* __restrict__ outF,
                                              u16* __restrict__ outB,
                                              int M, int N, int K) {
  __shared__ short As[16384];  // 128 x 128 bf16, 16B-chunk swizzled
  __shared__ short Bs[8192];   // 64 x 128
  int tid = threadIdx.x;
  int lane = tid & 63, wave = tid >> 6;
  int wr = wave >> 1, wc = wave & 1;
  int r = lane & 15, kg = lane >> 4;
  int row0 = blockIdx.x * 128, col0 = blockIdx.y * 64;

  f32x4 acc[4][2] = {};

  for (int kt = 0; kt < K; kt += 128) {
#pragma unroll
    for (int it = 0; it < 8; ++it) {
      int idx = it * 4096 + tid * 16;  // byte
      int rr = idx >> 8;
      int cl = (idx >> 4) & 15;
      int gc = cl ^ (rr & 15);
      *(short8*)((char*)As + idx) =
          *(const short8*)(A + (size_t)(row0 + rr) * K + kt + gc * 8);
    }
#pragma unroll
    for (int it = 0; it < 4; ++it) {
      int idx = it * 4096 + tid * 16;
      int rr = idx >> 8;
      int cl = (idx >> 4) & 15;
      int gc = cl ^ (rr & 15);
      *(short8*)((char*)Bs + idx) =
          *(const short8*)(W + (size_t)(col0 + rr) * K + kt + gc * 8);
    }
    __syncthreads();
#pragma unroll
    for (int ks = 0; ks < 4; ++ks) {
      int c = ks * 4 + kg;
      short8 bfr[2];
#pragma unroll
      for (int ni = 0; ni < 2; ++ni) {
        int rr = wc * 32 + ni * 16 + r;
        bfr[ni] = *(const short8*)((char*)Bs + rr * 256 + ((c ^ (rr & 15)) * 16));
      }
#pragma unroll
      for (int mi = 0; mi < 4; ++mi) {
        int rr = wr * 64 + mi * 16 + r;
        short8 afr = *(const short8*)((char*)As + rr * 256 + ((c ^ (rr & 15)) * 16));
#pragma unroll
        for (int ni = 0; ni < 2; ++ni)
          acc[mi][ni] = __builtin_amdgcn_mfma_f32_16x16x32_bf16(afr, bfr[ni], acc[mi][ni], 0, 0, 0);
      }
    }
    __syncthreads();
  }

#pragma unroll
  for (int mi = 0; mi < 4; ++mi) {
#pragma unroll
    for (int ni = 0; ni < 2; ++ni) {
      int c = col0 + wc * 32 + ni * 16 + r;
      float bs = bias[c];
#pragma unroll
      for (int e = 0; e < 4; ++e) {
        int rr = row0 + wr * 64 + mi * 16 + kg * 4 + e;
        float o = acc[mi][ni][e] + bs;
        if (ACT) o = 0.5f * o * (1.0f + erff(o * 0.7071067811865475f));
        if (RES) o += res[(size_t)rr * N + c];
        if (OUTBF) outB[(size_t)rr * N + c] = f2bf(o);
        else outF[(size_t)rr * N + c] = o;
      }
    }
  }
}

// ---------------- PROVEN (round 2): MFMA 7x7 neighborhood attention ----------------
// Block = 8x8 query tile, 4 waves (wave = head). qkv bf16 [tok][384].
__global__ __launch_bounds__(256) void k_natt(const u16* __restrict__ qkv,
                                              const float* __restrict__ rpb,
                                              u16* __restrict__ out) {
  __shared__ u16 VT[27136];  // [nd=128][212] V^T, bf16
  __shared__ u16 U[4352];    // bounce 32x136 | P 4x64x16
  __shared__ u16 rpbs[676];
  int tid = threadIdx.x;
  int lane = tid & 63, head = tid >> 6;
  int r = lane & 15, kg = lane >> 4;
  int bd = blockIdx.z;
  int th = blockIdx.y * 8, tw = blockIdx.x * 8;
  int u0h = min(max(th - 3, 0), 34);
  int u0w = min(max(tw - 3, 0), 34);
  int base = bd * HW_;

  for (int i = tid; i < 676; i += 256) rpbs[i] = f2bf(rpb[i]);

  // ---- stage V^T via bounce buffer ----
  for (int pass = 0; pass < 7; ++pass) {
    int jl = tid >> 3;            // 0..31
    int j = pass * 32 + jl;
    int c0 = (tid & 7) * 16;
    short8 v0 = {0, 0, 0, 0, 0, 0, 0, 0}, v1 = v0;
    if (j < 196) {
      int kh = u0h + j / 14, kw = u0w + j % 14;
      const u16* vp = qkv + (size_t)(base + kh * WDIM + kw) * 384 + 256 + c0;
      v0 = *(const short8*)vp;
      v1 = *(const short8*)(vp + 8);
    }
    __syncthreads();
    *(short8*)&U[jl * 136 + c0] = v0;
    *(short8*)&U[jl * 136 + c0 + 8] = v1;
    __syncthreads();
    int nd = tid & 127, jh = tid >> 7;
#pragma unroll
    for (int qq = 0; qq < 4; ++qq) {
      int j0 = pass * 32 + jh * 16 + qq * 4;
      if (j0 + 3 < 212) {
        int jb = jh * 16 + qq * 4;
        us4 pk;
        pk.x = U[(jb + 0) * 136 + nd];
        pk.y = U[(jb + 1) * 136 + nd];
        pk.z = U[(jb + 2) * 136 + nd];
        pk.w = U[(jb + 3) * 136 + nd];
        *(us4*)&VT[nd * 212 + j0] = pk;
      }
    }
  }
  __syncthreads();

  // per-lane query metadata + Q fragments (B-operand of swapped QK^T)
  int shq[4], swq[4], boff[4];
  short8 qf[4];
#pragma unroll
  for (int nt = 0; nt < 4; ++nt) {
    int q = nt * 16 + r;
    int hq = th + (q >> 3), wq = tw + (q & 7);
    shq[nt] = min(max(hq - 3, 0), 41);
    swq[nt] = min(max(wq - 3, 0), 41);
    boff[nt] = head * 169 + (6 - hq) * 13 + (6 - wq);
    qf[nt] = *(const short8*)(qkv + (size_t)(base + hq * WDIM + wq) * 384 + head * 32 + kg * 8);
  }

  f32x4 accO[4][2] = {};
  float rs[4] = {0.f, 0.f, 0.f, 0.f};
  u16* Pp = U + head * 1024;  // per-wave private P chunk [64 q][16 keys]

  for (int jt = 0; jt < 13; ++jt) {
    // K fragment (A-operand): lane row = key
    int key = jt * 16 + r;
    int uk = min(key, 195);
    int ktok = base + (u0h + uk / 14) * WDIM + (u0w + uk % 14);
    short8 kf = *(const short8*)(qkv + (size_t)ktok * 384 + 128 + head * 32 + kg * 8);
    f32x4 zero = {0.f, 0.f, 0.f, 0.f};
    f32x4 sv[4];
#pragma unroll
    for (int nt = 0; nt < 4; ++nt)
      sv[nt] = __builtin_amdgcn_mfma_f32_16x16x32_bf16(kf, qf[nt], zero, 0, 0, 0);

    int k0 = jt * 16 + kg * 4;
    int kh0 = k0 / 14;
    int kw0 = k0 - kh0 * 14;
#pragma unroll
    for (int nt = 0; nt < 4; ++nt) {
      float p[4];
#pragma unroll
      for (int e = 0; e < 4; ++e) {
        int khh = kh0, kww = kw0 + e;
        if (kww >= 14) { kww -= 14; khh += 1; }
        int kh = u0h + khh, kw = u0w + kww;
        bool valid = ((unsigned)(kh - shq[nt]) <= 6u) && ((unsigned)(kw - swq[nt]) <= 6u);
        int bidx = boff[nt] + kh * 13 + kw;
        bidx = valid ? bidx : 0;
        float sc = sv[nt][e] * 0.17677669529663687f + bf2f(rpbs[bidx]);
        p[e] = valid ? __expf(sc) : 0.f;  // scores are tiny; no max-shift needed
      }
      rs[nt] += (p[0] + p[1]) + (p[2] + p[3]);
      us4 pk;
      pk.x = f2bf(p[0]); pk.y = f2bf(p[1]); pk.z = f2bf(p[2]); pk.w = f2bf(p[3]);
      *(us4*)&Pp[(nt * 16 + r) * 16 + kg * 4] = pk;
    }
    __syncthreads();
    // PV: O[q][d] += P(64x16) * V(16x32), 16x16x16 mfma
#pragma unroll
    for (int mi = 0; mi < 4; ++mi) {
      sh4 af = *(const sh4*)&Pp[(mi * 16 + r) * 16 + kg * 4];
#pragma unroll
      for (int ni = 0; ni < 2; ++ni) {
        sh4 bfv = *(const sh4*)&VT[(head * 32 + ni * 16 + r) * 212 + jt * 16 + kg * 4];
        asm("v_mfma_f32_16x16x16_bf16 %0, %1, %2, %0"
            : "+v"(accO[mi][ni]) : "v"(af), "v"(bfv));
      }
    }
  }

  // softmax denominators: reduce over key-groups, then redistribute
#pragma unroll
  for (int nt = 0; nt < 4; ++nt) {
    rs[nt] += __shfl_xor(rs[nt], 16);
    rs[nt] += __shfl_xor(rs[nt], 32);
  }
  int cr4 = kg * 4;
#pragma unroll
  for (int mi = 0; mi < 4; ++mi) {
#pragma unroll
    for (int e = 0; e < 4; ++e) {
      float inv = 1.f / __shfl(rs[mi], cr4 + e);
      int q = mi * 16 + cr4 + e;
      int tok = base + (th + (q >> 3)) * WDIM + (tw + (q & 7));
#pragma unroll
      for (int ni = 0; ni < 2; ++ni)
        out[(size_t)tok * CDIM + head * 32 + ni * 16 + r] = f2bf(accO[mi][ni][e] * inv);
    }
  }
}

// ---------------- PROVEN (round 2): transpose out ----------------
__global__ __launch_bounds__(256) void k_transpose_out(const float* __restrict__ t2,
                                                       float* __restrict__ out) {
  __shared__ float tile[32][33];
  int bd = blockIdx.z; int b = bd >> 2, d = bd & 3;
  int s0 = blockIdx.x * 32, c0 = blockIdx.y * 32;
  int tx = threadIdx.x & 31, ty = threadIdx.x >> 5;
#pragma unroll
  for (int i = 0; i < 4; i++) {
    int s = s0 + ty + i * 8;
    tile[ty + i * 8][tx] = t2[((size_t)bd * HW_ + s) * CDIM + c0 + tx];
  }
  __syncthreads();
  size_t obase = (size_t)b * BCDHW + (size_t)d * HW_;
#pragma unroll
  for (int i = 0; i < 4; i++) {
    int c = c0 + ty + i * 8;
    out[obase + (size_t)c * DHW + s0 + tx] = tile[tx][ty + i * 8];
  }
}

extern "C" void kernel_launch(void* const* d_in, const int* in_sizes, int n_in,
                              void* d_out, int out_size, void* d_ws, size_t ws_size,
                              hipStream_t stream) {
  const float* x     = (const float*)d_in[0];
  const float* n1w   = (const float*)d_in[1];
  const float* n1b   = (const float*)d_in[2];
  const float* qkvw  = (const float*)d_in[3];
  const float* qkvb  = (const float*)d_in[4];
  const float* rpb   = (const float*)d_in[5];
  const float* projw = (const float*)d_in[6];
  const float* projb = (const float*)d_in[7];
  const float* n2w   = (const float*)d_in[8];
  const float* n2b   = (const float*)d_in[9];
  const float* fc1w  = (const float*)d_in[10];
  const float* fc1b  = (const float*)d_in[11];
  const float* fc2w  = (const float*)d_in[12];
  const float* fc2b  = (const float*)d_in[13];

  char* wsb = (char*)d_ws;
  float* t0   = (float*)wsb;                  //  9,437,184
  float* t1   = (float*)(wsb + 9437184);      //  9,437,184
  u16*   qkvB = (u16*)(wsb + 18874368);       // 14,155,776
  u16*   attb = (u16*)(wsb + 33030144);       //  4,718,592
  u16*   lnb  = (u16*)(wsb + 37748736);       //  4,718,592
  u16*   lnb2 = (u16*)(wsb + 42467328);       //  4,718,592
  u16*   h1b  = (u16*)(wsb + 47185920);       //  9,437,184
  u16*   wbf  = (u16*)(wsb + 56623104);       //    262,144
  float* t2   = t0;  // t0 dead after proj residual

  k_w2bf<<<512, 256, 0, stream>>>(qkvw, projw, fc1w, fc2w, wbf);
  k_fusein2<<<288, 256, 0, stream>>>(x, n1w, n1b, t0, lnb);
  k_gemm<0, 0, 1><<<dim3(144, 6), 256, 0, stream>>>(lnb, wbf, qkvb, nullptr,
                                                    nullptr, qkvB, NTOK, 384, 128);
  k_natt<<<dim3(6, 6, 8), 256, 0, stream>>>(qkvB, rpb, attb);
  k_gemm<0, 1, 0><<<dim3(144, 2), 256, 0, stream>>>(attb, wbf + 49152, projb, t0,
                                                    t1, nullptr, NTOK, 128, 128);
  k_ln<<<NTOK / 4, 256, 0, stream>>>(t1, n2w, n2b, lnb2);
  k_gemm<1, 0, 1><<<dim3(144, 4), 256, 0, stream>>>(lnb2, wbf + 65536, fc1b, nullptr,
                                                    nullptr, h1b, NTOK, 256, 128);
  k_gemm<0, 1, 0><<<dim3(144, 2), 256, 0, stream>>>(h1b, wbf + 98304, fc2b, t1,
                                                    t2, nullptr, NTOK, 128, 256);
  k_transpose_out<<<dim3(72, 4, 8), 256, 0, stream>>>(t2, (float*)d_out);
}